// Round 3
// baseline (232.843 us; speedup 1.0000x reference)
//
#include <hip/hip_runtime.h>

// FRFT with diagonal transform matrices (Evec = I in the reference):
//   out[n,c,h,w] = Re( D[(h+128)%256] * D[(w+128)%256] ) * x[n,c,h,w]
// where D[i] = 16 * exp(-i * (pi/2) * a * l_i),  l_i = i (i<255), l_255 = 256.
//
// HARNESS FACT (round-2 counters): the live output is the REAL part only,
// 134 MB float32 (WRITE_SIZE == 131072 KB == 16.7M x 8 B; out_npz ~125 MB).
// The interleaved complex path is kept only as a dead fallback.
//
// Round-4 change (the big one): 16 B/lane memory instructions both ways.
// Round-2/3 used dwordx2 (8 B/lane) loads AND stores and measured only
// 2.5 TB/s (31% HBM peak) at VALUBusy 12.5%, Occupancy 73% -> MLP-starved,
// not compute/occupancy-bound. Each thread now handles 4 consecutive
// elements: one f32x4 load + one f32x4 store (1 KB/wave per instruction,
// the m13 6.3 TB/s copy pattern). Side benefit: the per-lane w-table
// entries become loop-invariant (w0 = 4*(t&63)) so both ds_read_b128 table
// reads hoist out of the K-loop; only the wave-uniform ds_read_b64
// broadcast tbl[h] remains per iteration.

typedef float f32x2 __attribute__((ext_vector_type(2)));
typedef float f32x4 __attribute__((ext_vector_type(4)));

constexpr int HW    = 256;  // H == W == 256
constexpr int BLOCK = 256;
constexpr int KIT   = 8;    // f32x4 vectors per thread (32 elements)

__global__ __launch_bounds__(BLOCK) void frft_diag_kernel(
    const float* __restrict__ x,
    const float* __restrict__ order,
    float* __restrict__ out,
    int interleaved,
    int nvec4)   // number of f32x4 input vectors = total/4
{
    // Shifted diagonal table: entry i = 16 * (cos, sin) for index (i+128)%256.
    __shared__ alignas(16) f32x2 tbl[HW];

    const int t = threadIdx.x;
    // Build once per block. Double precision: phase reaches ~2400 rad;
    // double sincos keeps argument-reduction error negligible vs threshold.
    {
        const int idx = t ^ 128;                       // (t + 128) % 256
        const double l = (idx == 255) ? 256.0 : (double)idx;
        const double theta = 1.5707963267948966 * (double)order[0] * l;
        double s, c;
        sincos(theta, &s, &c);
        tbl[t] = (f32x2){(float)(16.0 * c), (float)(16.0 * s)};
    }
    __syncthreads();

    // Per-lane w-table entries are loop-invariant: element index e = 4p,
    // w = e & 255 = 4*(p & 63) = 4*(t & 63). Read once (one-time minor
    // bank conflicts, outside the hot loop).
    const int wbase = (t & 63) << 2;
    const f32x4 twA = *reinterpret_cast<const f32x4*>(&tbl[wbase]);      // c0,s0,c1,s1
    const f32x4 twB = *reinterpret_cast<const f32x4*>(&tbl[wbase + 2]);  // c2,s2,c3,s3

    const int base = blockIdx.x * (BLOCK * KIT) + t;

#pragma unroll
    for (int k = 0; k < KIT; ++k) {
        const int p = base + k * BLOCK;                // f32x4 index
        if (p >= nvec4) continue;                      // uniform; full blocks unaffected

        const f32x4 xv = ((const f32x4*)x)[p];         // global_load_dwordx4
        const f32x2 th = tbl[(p >> 6) & (HW - 1)];     // wave-uniform ds_read_b64

        // Re[(ch - i*sh)(cw - i*sw)] = ch*cw - sh*sw
        const float pr0 = th.x * twA.x - th.y * twA.y;
        const float pr1 = th.x * twA.z - th.y * twA.w;
        const float pr2 = th.x * twB.x - th.y * twB.y;
        const float pr3 = th.x * twB.z - th.y * twB.w;

        if (interleaved) {
            // Dead in this harness (output is real-only); kept for safety.
            const float pi0 = th.x * twA.y + th.y * twA.x;
            const float pi1 = th.x * twA.w + th.y * twA.z;
            const float pi2 = th.x * twB.y + th.y * twB.x;
            const float pi3 = th.x * twB.w + th.y * twB.z;
            f32x4 oA = { xv.x * pr0, -xv.x * pi0, xv.y * pr1, -xv.y * pi1 };
            f32x4 oB = { xv.z * pr2, -xv.z * pi2, xv.w * pr3, -xv.w * pi3 };
            __builtin_nontemporal_store(oA, &((f32x4*)out)[2 * p]);
            __builtin_nontemporal_store(oB, &((f32x4*)out)[2 * p + 1]);
        } else {
            f32x4 o = { xv.x * pr0, xv.y * pr1, xv.z * pr2, xv.w * pr3 };
            __builtin_nontemporal_store(o, &((f32x4*)out)[p]);  // dwordx4 nt
        }
    }
}

extern "C" void kernel_launch(void* const* d_in, const int* in_sizes, int n_in,
                              void* d_out, int out_size, void* d_ws, size_t ws_size,
                              hipStream_t stream) {
    const float* x     = (const float*)d_in[0];
    const float* order = (const float*)d_in[1];
    float* out = (float*)d_out;

    const int total = in_sizes[0];          // element count (divisible by 256)
    const int nvec4 = total / 4;            // f32x4 vectors
    const int interleaved = (out_size >= 2 * total) ? 1 : 0;

    const int per_block = BLOCK * KIT;      // 2048 f32x4 per block
    const int grid = (nvec4 + per_block - 1) / per_block;
    frft_diag_kernel<<<grid, BLOCK, 0, stream>>>(x, order, out, interleaved, nvec4);
}

// Round 4
// 229.935 us; speedup vs baseline: 1.0126x; 1.0126x over previous
//
#include <hip/hip_runtime.h>

// FRFT with diagonal transform matrices (Evec = I in the reference):
//   out[n,c,h,w] = Re( D[(h+128)%256] * D[(w+128)%256] ) * x[n,c,h,w]
// where D[i] = 16 * exp(-i * (pi/2) * a * l_i),  l_i = i (i<255), l_255 = 256.
//
// HARNESS FACTS (rocprof rounds 2-3):
//  - Live output is REAL-only, 134 MB f32 (WRITE_SIZE == 131072 KB).
//  - ~Half the input reads hit Infinity Cache (FETCH ~65 MB of 134 MB).
//  - Harness fill kernels sustain 6.7 TB/s with PLAIN stores.
//
// Round-5 changes (post-mortem of the 2.4 TB/s plateau):
//  1. DROP non-temporal stores. Both NT rounds (2,3) ran ~82 µs; the no-NT
//     round-0 baseline ran <79 µs. The fill proves plain stores through L2
//     sustain 6.7 TB/s on this chip; nt bypasses that path and lost BW.
//  2. Structurally force MLP: VGPR_Count=16 in rounds 2-3 meant the
//     compiler serialized load->wait->store (BW identical at 8 B/lane and
//     16 B/lane proved latency-, not width-bound). Now: batch-load KIT=4
//     f32x4 vectors into named registers FIRST (4 back-to-back
//     global_load_dwordx4, counted-vmcnt drain), then compute + store.
//  3. Keep 16 B/lane dense f32x4 on both sides; keep lane-invariant
//     w-table hoist; keep wave-uniform ds_read_b64 broadcast for tbl[h].

typedef float f32x2 __attribute__((ext_vector_type(2)));
typedef float f32x4 __attribute__((ext_vector_type(4)));

constexpr int HW    = 256;  // H == W == 256
constexpr int BLOCK = 256;
constexpr int KIT   = 4;    // f32x4 vectors per thread (16 elements)

__global__ __launch_bounds__(BLOCK) void frft_diag_kernel(
    const float* __restrict__ x,
    const float* __restrict__ order,
    float* __restrict__ out,
    int interleaved,
    int nvec4)   // number of f32x4 input vectors = total/4
{
    // Shifted diagonal table: entry i = 16 * (cos, sin) for index (i+128)%256.
    __shared__ alignas(16) f32x2 tbl[HW];

    const int t = threadIdx.x;
    // Build once per block. Double precision: phase reaches ~2400 rad;
    // double sincos keeps argument-reduction error negligible vs threshold.
    {
        const int idx = t ^ 128;                       // (t + 128) % 256
        const double l = (idx == 255) ? 256.0 : (double)idx;
        const double theta = 1.5707963267948966 * (double)order[0] * l;
        double s, c;
        sincos(theta, &s, &c);
        tbl[t] = (f32x2){(float)(16.0 * c), (float)(16.0 * s)};
    }
    __syncthreads();

    // Element index e = 4p, so w = e & 255 = 4*(p & 63) = 4*(t & 63):
    // lane-invariant across the whole kernel. Hoist both table quads.
    const int wbase = (t & 63) << 2;
    const f32x4 twA = *reinterpret_cast<const f32x4*>(&tbl[wbase]);      // c0,s0,c1,s1
    const f32x4 twB = *reinterpret_cast<const f32x4*>(&tbl[wbase + 2]);  // c2,s2,c3,s3

    const int base = blockIdx.x * (BLOCK * KIT) + t;   // f32x4 index, k-stride BLOCK

    // ---- Phase 1: issue all KIT loads back-to-back (batched vmcnt) ----
    f32x4 xv0, xv1, xv2, xv3;
    {
        const int p0 = base;
        const int p1 = base + BLOCK;
        const int p2 = base + 2 * BLOCK;
        const int p3 = base + 3 * BLOCK;
        xv0 = (p0 < nvec4) ? ((const f32x4*)x)[p0] : (f32x4){0, 0, 0, 0};
        xv1 = (p1 < nvec4) ? ((const f32x4*)x)[p1] : (f32x4){0, 0, 0, 0};
        xv2 = (p2 < nvec4) ? ((const f32x4*)x)[p2] : (f32x4){0, 0, 0, 0};
        xv3 = (p3 < nvec4) ? ((const f32x4*)x)[p3] : (f32x4){0, 0, 0, 0};
    }

    // ---- Phase 2: per-vector h-factor, compute, plain dwordx4 store ----
#pragma unroll
    for (int k = 0; k < KIT; ++k) {
        const int p = base + k * BLOCK;
        if (p >= nvec4) continue;
        const f32x4 xv = (k == 0) ? xv0 : (k == 1) ? xv1 : (k == 2) ? xv2 : xv3;

        const f32x2 th = tbl[(p >> 6) & (HW - 1)];     // wave-uniform ds_read_b64

        // Re[(ch - i*sh)(cw - i*sw)] = ch*cw - sh*sw
        const float pr0 = th.x * twA.x - th.y * twA.y;
        const float pr1 = th.x * twA.z - th.y * twA.w;
        const float pr2 = th.x * twB.x - th.y * twB.y;
        const float pr3 = th.x * twB.z - th.y * twB.w;

        if (interleaved) {
            // Dead in this harness (output is real-only); kept for safety.
            const float pi0 = th.x * twA.y + th.y * twA.x;
            const float pi1 = th.x * twA.w + th.y * twA.z;
            const float pi2 = th.x * twB.y + th.y * twB.x;
            const float pi3 = th.x * twB.w + th.y * twB.z;
            f32x4 oA = { xv.x * pr0, -xv.x * pi0, xv.y * pr1, -xv.y * pi1 };
            f32x4 oB = { xv.z * pr2, -xv.z * pi2, xv.w * pr3, -xv.w * pi3 };
            ((f32x4*)out)[2 * p]     = oA;
            ((f32x4*)out)[2 * p + 1] = oB;
        } else {
            f32x4 o = { xv.x * pr0, xv.y * pr1, xv.z * pr2, xv.w * pr3 };
            ((f32x4*)out)[p] = o;                      // plain global_store_dwordx4
        }
    }
}

extern "C" void kernel_launch(void* const* d_in, const int* in_sizes, int n_in,
                              void* d_out, int out_size, void* d_ws, size_t ws_size,
                              hipStream_t stream) {
    const float* x     = (const float*)d_in[0];
    const float* order = (const float*)d_in[1];
    float* out = (float*)d_out;

    const int total = in_sizes[0];          // element count (divisible by 256^2)
    const int nvec4 = total / 4;            // f32x4 vectors
    const int interleaved = (out_size >= 2 * total) ? 1 : 0;

    const int per_block = BLOCK * KIT;      // 1024 f32x4 per block
    const int grid = (nvec4 + per_block - 1) / per_block;
    frft_diag_kernel<<<grid, BLOCK, 0, stream>>>(x, order, out, interleaved, nvec4);
}